// Round 16
// baseline (1037.861 us; speedup 1.0000x reference)
//
#include <hip/hip_runtime.h>

// HWTV: ADMM TV solver, 124 independent 128x128 images, 20 iterations.
// One workgroup per image; whole iteration loop in-kernel.
// Round 19: RETRY R17 (never executed -- container failed twice; evidence
// points to infra flake: no compile error surfaced, and this harness showed
// severe push degradation in adjacent rounds. R4/R5 already exercised the
// full-unroll spill-storm compile path without incident).
// Theory (unfalsified): the 64-register pin is the allocator's occupancy
// heuristic not consulting LDS-bound occupancy. launch_bounds(,4)/(,1),
// waves_per_eu(4,4), and static-LDS occupancy math were all ignored, but
// __attribute__((amdgpu_num_vgpr(128))) is the DIRECT budget request and
// was never measured. Full unroll of the five state loops is a required
// co-payload (runtime-indexed arrays go to scratch at any budget).
//   - Honored: a/g1/bh/bv (64 floats) become registers -> zero spill,
//     FETCH <100MB, ~480-560us. [tell: VGPR_Count ~128]
//   - Ignored: R4-like spill storm (~1400us) -> revert to R12 next round.
// FFT section bit-identical to R12 (661us champion): radix-4(TW) x2 +
// radix-8(const twiddles) per dim; cols fwd-r8 + solve + inv-r8 fused
// in-register; SW(c)=c^(c>>3) bank swizzle.

#define NPIX   16384
#define NSIDE  128
#define NIMG   124
#define NT     1024
#define PXT    16          // pixels per thread
#define N_ITE  20
#define LAM_F  0.1f
#define RHO_F  1.05f
#define PI_F   3.14159265358979323846f

// physical column swizzle: spreads FFT strided row-access sets across banks
#define SW(c) ((c) ^ ((c) >> 3))

__device__ __forceinline__ float2 cadd(float2 a, float2 b) {
    return make_float2(a.x + b.x, a.y + b.y);
}
__device__ __forceinline__ float2 csub(float2 a, float2 b) {
    return make_float2(a.x - b.x, a.y - b.y);
}
__device__ __forceinline__ float2 cmul(float2 a, float2 w) {
    return make_float2(fmaf(a.x, w.x, -(a.y * w.y)),
                       fmaf(a.x, w.y,  (a.y * w.x)));
}
__device__ __forceinline__ float2 cmulc(float2 a, float2 w) {   // a * conj(w)
    return make_float2(fmaf(a.x, w.x,  (a.y * w.y)),
                       fmaf(a.y, w.x, -(a.x * w.y)));
}

#define RT2H 0.70710678118654752f   // sqrt(2)/2

// forward radix-8 (DIF stages len=4,2,1), constant twiddles (W8/W4 powers)
__device__ __forceinline__ void radix8_fwd(float2 z[8]) {
    float2 A0 = cadd(z[0], z[4]), A1 = cadd(z[1], z[5]);
    float2 A2 = cadd(z[2], z[6]), A3 = cadd(z[3], z[7]);
    float2 d0 = csub(z[0], z[4]), d1 = csub(z[1], z[5]);
    float2 d2 = csub(z[2], z[6]), d3 = csub(z[3], z[7]);
    float2 B0 = d0;                                            // *W8^0
    float2 B1 = make_float2(RT2H*(d1.x + d1.y), RT2H*(d1.y - d1.x)); // *(c,-c)
    float2 B2 = make_float2(d2.y, -d2.x);                      // *(-i)
    float2 B3 = make_float2(RT2H*(d3.y - d3.x), -RT2H*(d3.x + d3.y)); // *(-c,-c)
    float2 C0 = cadd(A0, A2), C2 = csub(A0, A2);
    float2 t13 = csub(A1, A3);
    float2 C1 = cadd(A1, A3);
    float2 C3 = make_float2(t13.y, -t13.x);                    // *(-i)
    float2 E0 = cadd(B0, B2), E2 = csub(B0, B2);
    float2 u13 = csub(B1, B3);
    float2 E1 = cadd(B1, B3);
    float2 E3 = make_float2(u13.y, -u13.x);
    z[0] = cadd(C0, C1);  z[1] = csub(C0, C1);
    z[2] = cadd(C2, C3);  z[3] = csub(C2, C3);
    z[4] = cadd(E0, E1);  z[5] = csub(E0, E1);
    z[6] = cadd(E2, E3);  z[7] = csub(E2, E3);
}

// inverse radix-8 (DIT stages len=1,2,4), constant twiddles
__device__ __forceinline__ void radix8_inv(float2 z[8]) {
    float2 a0 = cadd(z[0], z[1]), a1 = csub(z[0], z[1]);
    float2 a2 = cadd(z[2], z[3]), a3 = csub(z[2], z[3]);
    float2 a4 = cadd(z[4], z[5]), a5 = csub(z[4], z[5]);
    float2 a6 = cadd(z[6], z[7]), a7 = csub(z[6], z[7]);
    float2 b0 = cadd(a0, a2), b2 = csub(a0, a2);
    float2 t3 = make_float2(-a3.y, a3.x);                      // a3 * (+i)
    float2 b1 = cadd(a1, t3), b3 = csub(a1, t3);
    float2 b4 = cadd(a4, a6), b6 = csub(a4, a6);
    float2 t7 = make_float2(-a7.y, a7.x);
    float2 b5 = cadd(a5, t7), b7 = csub(a5, t7);
    float2 p0 = b4;                                            // *conj(W8^0)
    float2 p1 = make_float2(RT2H*(b5.x - b5.y), RT2H*(b5.x + b5.y)); // *(c,c)
    float2 p2 = make_float2(-b6.y, b6.x);                      // *(+i)
    float2 p3 = make_float2(-RT2H*(b7.x + b7.y), RT2H*(b7.x - b7.y)); // *(-c,c)
    z[0] = cadd(b0, p0);  z[4] = csub(b0, p0);
    z[1] = cadd(b1, p1);  z[5] = csub(b1, p1);
    z[2] = cadd(b2, p2);  z[6] = csub(b2, p2);
    z[3] = cadd(b3, p3);  z[7] = csub(b3, p3);
}

__global__
__attribute__((amdgpu_flat_work_group_size(1024, 1024)))
__attribute__((amdgpu_waves_per_eu(4, 4)))
__attribute__((amdgpu_num_vgpr(128)))
void hwtv_kernel(
    const float* __restrict__ Yg,
    const float* __restrict__ Wg,
    float* __restrict__ outg)
{
    __shared__ float2 C[NPIX];     // 128 KB
    __shared__ float2 TW[64];      // twiddles W_128^k
    __shared__ float  D1[NSIDE];   // 4sin^2(pi*bitrev7(i)/128)

    const int tid = threadIdx.x;
    const size_t base  = (size_t)blockIdx.x * NPIX;
    const float* Y  = Yg + base;
    const float* Wt = Wg + base;
    float* out = outg + base;

    // ---- one-time tables + Z0 = Y into LDS ----
    if (tid < 64) {
        float ang = -2.0f * PI_F * (float)tid / 128.0f;
        TW[tid] = make_float2(cosf(ang), sinf(ang));
    }
    if (tid < 128) {
        int br = (int)(__brev((unsigned)tid) >> 25);       // bitrev7
        float s = sinf(PI_F * (float)br / 128.0f);
        D1[tid] = 4.0f * s * s;
    }

    // persistent per-thread state, FULLY UNROLLED -> SSA (registers if the
    // 128-VGPR request is honored):
    //   a  = mu1*X + G1, g1 = G1,
    //   bh = mu2*Uh + G21, bv = mu2*Uv + G22
    float a[PXT], g1[PXT], bh[PXT], bv[PXT];
    #pragma unroll
    for (int k = 0; k < PXT; ++k) {
        int p = tid + k * NT;
        int col = p & (NSIDE - 1);
        int rowb = p & ~(NSIDE - 1);
        float y = Y[p];
        C[rowb + SW(col)] = make_float2(y, 0.0f);   // Z0 = Y
        a[k]  = 0.1f * y;                // mu1*X0 + G1_0 = mu1*Y
        g1[k] = 0.0f;
        bh[k] = 0.0f;
        bv[k] = 0.0f;
    }
    __syncthreads();

    float mu1 = 0.1f, mu2 = 0.1f;

    for (int it = 0; it < N_ITE; ++it) {
        const float mu2p   = mu2 * (1.0f / RHO_F);  // previous iteration's mu2
        const float inv_m2 = 1.0f / mu2;
        const float thr    = LAM_F * inv_m2;

        // ---- P1: shrink; bh_new = mu2*Uh + G21, bv_new = mu2*Uv + G22 ----
        #pragma unroll
        for (int k = 0; k < PXT; ++k) {
            int p    = tid + k * NT;
            int col  = p & (NSIDE - 1);
            int rowb = p & ~(NSIDE - 1);
            int sc_  = SW(col);
            float z  = C[rowb + sc_].x;
            float zl = C[rowb + SW((col + NSIDE - 1) & (NSIDE - 1))].x;
            int pu   = (p + NPIX - NSIDE) & (NPIX - 1);
            float zu = C[(pu & ~(NSIDE - 1)) + sc_].x;
            float dhz = z - zl;
            float dvz = z - zu;
            float g21 = (it == 0) ? 0.0f : fmaf(-mu2p, dhz, bh[k]);
            float g22 = (it == 0) ? 0.0f : fmaf(-mu2p, dvz, bv[k]);
            float ah = dhz - g21 * inv_m2;
            float av = dvz - g22 * inv_m2;
            float uh = copysignf(fmaxf(fabsf(ah) - thr, 0.0f), ah);
            float uv = copysignf(fmaxf(fabsf(av) - thr, 0.0f), av);
            bh[k] = fmaf(mu2, uh, g21);
            bv[k] = fmaf(mu2, uv, g22);
        }
        __syncthreads();          // all Z reads done before overwriting C

        // ---- P2: stage (bh, bv) in C for neighbor exchange ----
        #pragma unroll
        for (int k = 0; k < PXT; ++k) {
            int p = tid + k * NT;
            int col = p & (NSIDE - 1);
            int rowb = p & ~(NSIDE - 1);
            C[rowb + SW(col)] = make_float2(bh[k], bv[k]);
        }
        __syncthreads();

        // ---- P3: numerator = a + Dh^T bh + Dv^T bv ----
        float numv[PXT];
        #pragma unroll
        for (int k = 0; k < PXT; ++k) {
            int p    = tid + k * NT;
            int col  = p & (NSIDE - 1);
            int rowb = p & ~(NSIDE - 1);
            int sc_  = SW(col);
            float bhr = C[rowb + SW((col + 1) & (NSIDE - 1))].x;
            int pd    = (p + NSIDE) & (NPIX - 1);
            float bvd = C[(pd & ~(NSIDE - 1)) + sc_].y;
            numv[k] = a[k] + (bh[k] - bhr) + (bv[k] - bvd);
        }
        __syncthreads();          // all neighbor reads done before overwrite

        // ---- P4: C <- numerator (real) ----
        #pragma unroll
        for (int k = 0; k < PXT; ++k) {
            int p = tid + k * NT;
            int col = p & (NSIDE - 1);
            int rowb = p & ~(NSIDE - 1);
            C[rowb + SW(col)] = make_float2(numv[k], 0.0f);
        }
        __syncthreads();

        // ================= forward FFT over rows =================
        #define FWD_ROW_PASS(S, L2)                                          \
        {                                                                    \
            _Pragma("unroll 2")                                              \
            for (int q = 0; q < 4; ++q) {                                    \
                int m   = tid + q * NT;                                      \
                int rb  = (m >> 5) << 7;                                     \
                int b   = m & 31;                                            \
                int j   = b & ((L2) - 1);                                    \
                int i0  = ((b & ~((L2) - 1)) << 2) | j;                      \
                int e0 = rb + SW(i0);                                        \
                int e1 = rb + SW(i0 + (L2));                                 \
                int e2 = rb + SW(i0 + 2*(L2));                               \
                int e3 = rb + SW(i0 + 3*(L2));                               \
                float2 w1 = TW[j << (S)];                                    \
                float2 w2 = cmul(w1, w1);                                    \
                float2 x0 = C[e0], x1 = C[e1];                               \
                float2 x2 = C[e2], x3 = C[e3];                               \
                float2 t02p = cadd(x0, x2);                                  \
                float2 t13p = cadd(x1, x3);                                  \
                float2 t02m = cmul(csub(x0, x2), w1);                        \
                float2 uu   = cmul(csub(x1, x3), w1);                        \
                float2 t13m = make_float2(uu.y, -uu.x);   /* * (-i) */       \
                C[e0] = cadd(t02p, t13p);                                    \
                C[e1] = cmul(csub(t02p, t13p), w2);                          \
                C[e2] = cadd(t02m, t13m);                                    \
                C[e3] = cmul(csub(t02m, t13m), w2);                          \
            }                                                                \
            __syncthreads();                                                 \
        }
        FWD_ROW_PASS(0, 32)
        FWD_ROW_PASS(2, 8)
        // radix-8 pass: stages 4,5,6 on 8 consecutive cols (const twiddles)
        {
            #pragma unroll 2
            for (int q = 0; q < 2; ++q) {
                int m  = tid + q * NT;          // 0..2047 group index
                int rb = (m >> 4) << 7;         // row*128
                int cb = (m & 15) << 3;         // base col
                float2 zz[8];
                #pragma unroll
                for (int i = 0; i < 8; ++i) zz[i] = C[rb + SW(cb + i)];
                radix8_fwd(zz);
                #pragma unroll
                for (int i = 0; i < 8; ++i) C[rb + SW(cb + i)] = zz[i];
            }
            __syncthreads();
        }

        // ================= forward FFT over cols (2 radix-4 passes) =======
        #define FWD_COL_PASS(S, L2)                                          \
        {                                                                    \
            _Pragma("unroll 2")                                              \
            for (int q = 0; q < 4; ++q) {                                    \
                int m  = tid + q * NT;                                       \
                int c  = m & 127;                                            \
                int b  = m >> 7;                                             \
                int j  = b & ((L2) - 1);                                     \
                int i0 = ((b & ~((L2) - 1)) << 2) | j;                       \
                int p0 = (i0 << 7) + SW(c);                                  \
                const int ST = (L2) << 7;                                    \
                float2 w1 = TW[j << (S)];                                    \
                float2 w2 = cmul(w1, w1);                                    \
                float2 x0 = C[p0], x1 = C[p0 + ST];                          \
                float2 x2 = C[p0 + 2*ST], x3 = C[p0 + 3*ST];                 \
                float2 t02p = cadd(x0, x2);                                  \
                float2 t13p = cadd(x1, x3);                                  \
                float2 t02m = cmul(csub(x0, x2), w1);                        \
                float2 uu   = cmul(csub(x1, x3), w1);                        \
                float2 t13m = make_float2(uu.y, -uu.x);                      \
                C[p0]        = cadd(t02p, t13p);                             \
                C[p0 +   ST] = cmul(csub(t02p, t13p), w2);                   \
                C[p0 + 2*ST] = cadd(t02m, t13m);                             \
                C[p0 + 3*ST] = cmul(csub(t02m, t13m), w2);                   \
            }                                                                \
            __syncthreads();                                                 \
        }
        FWD_COL_PASS(0, 32)
        FWD_COL_PASS(2, 8)

        // ==== MEGA-PASS: cols fwd radix-8 (s=4,5,6) + solve x8 +
        //      cols inverse radix-8 (s=0,1,2), all in registers ====
        {
            const float sc = 1.0f / (float)NPIX;
            #pragma unroll 2
            for (int q = 0; q < 2; ++q) {
                int m   = tid + q * NT;
                int col = m & 127;
                int g   = m >> 7;               // 0..15 row-group
                int r0  = g << 3;               // base row
                int p0  = (r0 << 7) + SW(col);
                float2 zz[8];
                #pragma unroll
                for (int i = 0; i < 8; ++i) zz[i] = C[p0 + (i << 7)];
                radix8_fwd(zz);
                float d1c = D1[col];
                #pragma unroll
                for (int i = 0; i < 8; ++i) {
                    float f = sc / fmaf(mu2, D1[r0 + i] + d1c, mu1);
                    zz[i].x *= f; zz[i].y *= f;
                }
                radix8_inv(zz);
                #pragma unroll
                for (int i = 0; i < 8; ++i) C[p0 + (i << 7)] = zz[i];
            }
            __syncthreads();
        }

        // ================= inverse FFT over cols (2 radix-4 passes) =======
        #define INV_COL_PASS(SB, M)                                          \
        {                                                                    \
            _Pragma("unroll 2")                                              \
            for (int q = 0; q < 4; ++q) {                                    \
                int m  = tid + q * NT;                                       \
                int c  = m & 127;                                            \
                int b  = m >> 7;                                             \
                int j  = b & ((M) - 1);                                      \
                int i0 = ((b & ~((M) - 1)) << 2) | j;                        \
                int p0 = (i0 << 7) + SW(c);                                  \
                const int ST = (M) << 7;                                     \
                float2 wb = TW[j << (SB)];                                   \
                float2 wa = cmul(wb, wb);                                    \
                float2 x0 = C[p0], x1 = C[p0 + ST];                          \
                float2 x2 = C[p0 + 2*ST], x3 = C[p0 + 3*ST];                 \
                float2 pp1 = cmulc(x1, wa);                                  \
                float2 a0 = cadd(x0, pp1), a1 = csub(x0, pp1);               \
                float2 pp2 = cmulc(x3, wa);                                  \
                float2 a2 = cadd(x2, pp2), a3 = csub(x2, pp2);               \
                float2 q0 = cmulc(a2, wb);                                   \
                float2 y0 = cadd(a0, q0), y2 = csub(a0, q0);                 \
                float2 uu = cmulc(a3, wb);                                   \
                float2 q1 = make_float2(-uu.y, uu.x);     /* * (+i) */       \
                float2 y1 = cadd(a1, q1), y3 = csub(a1, q1);                 \
                C[p0]        = y0;                                           \
                C[p0 +   ST] = y1;                                           \
                C[p0 + 2*ST] = y2;                                           \
                C[p0 + 3*ST] = y3;                                           \
            }                                                                \
            __syncthreads();                                                 \
        }
        INV_COL_PASS(2, 8)
        INV_COL_PASS(0, 32)

        // ================= inverse FFT over rows =================
        // radix-8 pass: stages 0,1,2 on 8 consecutive cols (const twiddles)
        {
            #pragma unroll 2
            for (int q = 0; q < 2; ++q) {
                int m  = tid + q * NT;
                int rb = (m >> 4) << 7;
                int cb = (m & 15) << 3;
                float2 zz[8];
                #pragma unroll
                for (int i = 0; i < 8; ++i) zz[i] = C[rb + SW(cb + i)];
                radix8_inv(zz);
                #pragma unroll
                for (int i = 0; i < 8; ++i) C[rb + SW(cb + i)] = zz[i];
            }
            __syncthreads();
        }
        #define INV_ROW_PASS(SB, M)                                          \
        {                                                                    \
            _Pragma("unroll 2")                                              \
            for (int q = 0; q < 4; ++q) {                                    \
                int m   = tid + q * NT;                                      \
                int rb  = (m >> 5) << 7;                                     \
                int b   = m & 31;                                            \
                int j   = b & ((M) - 1);                                     \
                int i0  = ((b & ~((M) - 1)) << 2) | j;                       \
                int e0 = rb + SW(i0);                                        \
                int e1 = rb + SW(i0 + (M));                                  \
                int e2 = rb + SW(i0 + 2*(M));                                \
                int e3 = rb + SW(i0 + 3*(M));                                \
                float2 wb = TW[j << (SB)];                                   \
                float2 wa = cmul(wb, wb);                                    \
                float2 x0 = C[e0], x1 = C[e1];                               \
                float2 x2 = C[e2], x3 = C[e3];                               \
                float2 pp1 = cmulc(x1, wa);                                  \
                float2 a0 = cadd(x0, pp1), a1 = csub(x0, pp1);               \
                float2 pp2 = cmulc(x3, wa);                                  \
                float2 a2 = cadd(x2, pp2), a3 = csub(x2, pp2);               \
                float2 q0 = cmulc(a2, wb);                                   \
                float2 y0 = cadd(a0, q0), y2 = csub(a0, q0);                 \
                float2 uu = cmulc(a3, wb);                                   \
                float2 q1 = make_float2(-uu.y, uu.x);                        \
                float2 y1 = cadd(a1, q1), y3 = csub(a1, q1);                 \
                C[e0] = y0;                                                  \
                C[e1] = y1;                                                  \
                C[e2] = y2;                                                  \
                C[e3] = y3;                                                  \
            }                                                                \
            __syncthreads();                                                 \
        }
        INV_ROW_PASS(2, 8)
        INV_ROW_PASS(0, 32)

        // ---- Epilogue: X/G1/a update in registers; Z stays in C[].x ----
        const float mu1n = mu1 * RHO_F;
        #pragma unroll
        for (int k = 0; k < PXT; ++k) {
            int p = tid + k * NT;
            int col = p & (NSIDE - 1);
            int rowb = p & ~(NSIDE - 1);
            float z  = C[rowb + SW(col)].x;
            float y  = Y[p];
            float w  = Wt[p];
            float x  = fmaf(w, y, fmaf(mu1, z, -g1[k])) *
                       __builtin_amdgcn_rcpf(w + mu1);
            g1[k] = fmaf(mu1, x - z, g1[k]);
            a[k]  = fmaf(mu1n, x, g1[k]);
            if (it == N_ITE - 1) out[p] = z;
        }
        // no barrier needed: next P1 only reads C (covered by the FFT's last
        // barrier); P2's writes are behind P1's barrier.

        mu1 *= RHO_F;
        mu2 *= RHO_F;
    }
}

extern "C" void kernel_launch(void* const* d_in, const int* in_sizes, int n_in,
                              void* d_out, int out_size, void* d_ws, size_t ws_size,
                              hipStream_t stream) {
    (void)in_sizes; (void)n_in; (void)out_size; (void)d_ws; (void)ws_size;
    const float* Y   = (const float*)d_in[0];
    const float* inW = (const float*)d_in[1];
    float* out = (float*)d_out;

    hipLaunchKernelGGL(hwtv_kernel, dim3(NIMG), dim3(NT), 0, stream,
                       Y, inW, out);
}

// Round 17
// 661.098 us; speedup vs baseline: 1.5699x; 1.5699x over previous
//
#include <hip/hip_runtime.h>

// HWTV: ADMM TV solver, 124 independent 128x128 images, 20 iterations.
// One workgroup per image; whole iteration loop in-kernel.
// Round 20 (FINAL): restore R12 (session champion, 660.8/662.5/661.2us
// across three runs). R19 measured the last untried register-budget channel:
// __attribute__((amdgpu_num_vgpr(128))) was IGNORED (VGPR_Count stayed 64)
// and the full-unroll payload spilled as predicted (806MB FETCH, 1038us).
// All EIGHT mechanisms for relocating the 64 persistent floats/thread of
// ADMM state are now falsified: launch_bounds(,4)/(,1), waves_per_eu(4,4),
// static-LDS occupancy, volatile planes (HBM-bypass), asm-opaque planes,
// AGPR homes (unified file), amdgpu_num_vgpr. The 64-register pin is not
// reachable from HIP source on this toolchain; slim loops + compiler-managed
// coalesced scratch (this kernel) is the measured optimum.
// Final ladder: 1225 -> 872.8 (radix-4 fused FFT) -> 779.0 (SW bank
// swizzle) -> 660.8us (radix-8 const-twiddle passes + fused solve
// mega-pass). 1.85x total. Not a HW roofline (LDS ~30%, VALU 24%, HBM 13%)
// -- a toolchain-imposed local optimum.
// Structure: radix-4 fused FFT passes (TW twiddles) x2 per dim per
// direction; radix-8 passes (constant twiddles) for distance<=4 stages;
// cols fwd-r8 + solve + inv-r8 fused into one in-register mega-pass;
// SW(c)=c^(c>>3) LDS bank swizzle; 11 FFT LDS passes + 4 state passes,
// 15 barriers per iteration.

#define NPIX   16384
#define NSIDE  128
#define NIMG   124
#define NT     1024
#define PXT    16          // pixels per thread
#define N_ITE  20
#define LAM_F  0.1f
#define RHO_F  1.05f
#define PI_F   3.14159265358979323846f

// physical column swizzle: spreads FFT strided row-access sets across banks
#define SW(c) ((c) ^ ((c) >> 3))

__device__ __forceinline__ float2 cadd(float2 a, float2 b) {
    return make_float2(a.x + b.x, a.y + b.y);
}
__device__ __forceinline__ float2 csub(float2 a, float2 b) {
    return make_float2(a.x - b.x, a.y - b.y);
}
__device__ __forceinline__ float2 cmul(float2 a, float2 w) {
    return make_float2(fmaf(a.x, w.x, -(a.y * w.y)),
                       fmaf(a.x, w.y,  (a.y * w.x)));
}
__device__ __forceinline__ float2 cmulc(float2 a, float2 w) {   // a * conj(w)
    return make_float2(fmaf(a.x, w.x,  (a.y * w.y)),
                       fmaf(a.y, w.x, -(a.x * w.y)));
}

#define RT2H 0.70710678118654752f   // sqrt(2)/2

// forward radix-8 (DIF stages len=4,2,1), constant twiddles (W8/W4 powers)
__device__ __forceinline__ void radix8_fwd(float2 z[8]) {
    float2 A0 = cadd(z[0], z[4]), A1 = cadd(z[1], z[5]);
    float2 A2 = cadd(z[2], z[6]), A3 = cadd(z[3], z[7]);
    float2 d0 = csub(z[0], z[4]), d1 = csub(z[1], z[5]);
    float2 d2 = csub(z[2], z[6]), d3 = csub(z[3], z[7]);
    float2 B0 = d0;                                            // *W8^0
    float2 B1 = make_float2(RT2H*(d1.x + d1.y), RT2H*(d1.y - d1.x)); // *(c,-c)
    float2 B2 = make_float2(d2.y, -d2.x);                      // *(-i)
    float2 B3 = make_float2(RT2H*(d3.y - d3.x), -RT2H*(d3.x + d3.y)); // *(-c,-c)
    float2 C0 = cadd(A0, A2), C2 = csub(A0, A2);
    float2 t13 = csub(A1, A3);
    float2 C1 = cadd(A1, A3);
    float2 C3 = make_float2(t13.y, -t13.x);                    // *(-i)
    float2 E0 = cadd(B0, B2), E2 = csub(B0, B2);
    float2 u13 = csub(B1, B3);
    float2 E1 = cadd(B1, B3);
    float2 E3 = make_float2(u13.y, -u13.x);
    z[0] = cadd(C0, C1);  z[1] = csub(C0, C1);
    z[2] = cadd(C2, C3);  z[3] = csub(C2, C3);
    z[4] = cadd(E0, E1);  z[5] = csub(E0, E1);
    z[6] = cadd(E2, E3);  z[7] = csub(E2, E3);
}

// inverse radix-8 (DIT stages len=1,2,4), constant twiddles
__device__ __forceinline__ void radix8_inv(float2 z[8]) {
    float2 a0 = cadd(z[0], z[1]), a1 = csub(z[0], z[1]);
    float2 a2 = cadd(z[2], z[3]), a3 = csub(z[2], z[3]);
    float2 a4 = cadd(z[4], z[5]), a5 = csub(z[4], z[5]);
    float2 a6 = cadd(z[6], z[7]), a7 = csub(z[6], z[7]);
    float2 b0 = cadd(a0, a2), b2 = csub(a0, a2);
    float2 t3 = make_float2(-a3.y, a3.x);                      // a3 * (+i)
    float2 b1 = cadd(a1, t3), b3 = csub(a1, t3);
    float2 b4 = cadd(a4, a6), b6 = csub(a4, a6);
    float2 t7 = make_float2(-a7.y, a7.x);
    float2 b5 = cadd(a5, t7), b7 = csub(a5, t7);
    float2 p0 = b4;                                            // *conj(W8^0)
    float2 p1 = make_float2(RT2H*(b5.x - b5.y), RT2H*(b5.x + b5.y)); // *(c,c)
    float2 p2 = make_float2(-b6.y, b6.x);                      // *(+i)
    float2 p3 = make_float2(-RT2H*(b7.x + b7.y), RT2H*(b7.x - b7.y)); // *(-c,c)
    z[0] = cadd(b0, p0);  z[4] = csub(b0, p0);
    z[1] = cadd(b1, p1);  z[5] = csub(b1, p1);
    z[2] = cadd(b2, p2);  z[6] = csub(b2, p2);
    z[3] = cadd(b3, p3);  z[7] = csub(b3, p3);
}

__global__ __launch_bounds__(NT, 4) void hwtv_kernel(
    const float* __restrict__ Yg,
    const float* __restrict__ Wg,
    float* __restrict__ outg)
{
    extern __shared__ char smem[];
    float2* C  = (float2*)smem;                            // 16384 complex (128 KB)
    float2* TW = (float2*)(smem + (size_t)NPIX * 8);       // 64 twiddles W_128^k
    float*  D1 = (float*)(smem + (size_t)NPIX * 8 + 64*8); // 128: 4sin^2(pi*bitrev7(i)/128)

    const int tid = threadIdx.x;
    const size_t base  = (size_t)blockIdx.x * NPIX;
    const float* Y  = Yg + base;
    const float* Wt = Wg + base;
    float* out = outg + base;

    // ---- one-time tables + Z0 = Y into LDS ----
    if (tid < 64) {
        float ang = -2.0f * PI_F * (float)tid / 128.0f;
        TW[tid] = make_float2(cosf(ang), sinf(ang));
    }
    if (tid < 128) {
        int br = (int)(__brev((unsigned)tid) >> 25);       // bitrev7
        float s = sinf(PI_F * (float)br / 128.0f);
        D1[tid] = 4.0f * s * s;
    }

    float a[PXT], g1[PXT], bh[PXT], bv[PXT];
    #pragma unroll
    for (int k = 0; k < PXT; ++k) {
        int p = tid + k * NT;
        int col = p & (NSIDE - 1);
        int rowb = p & ~(NSIDE - 1);
        float y = Y[p];
        C[rowb + SW(col)] = make_float2(y, 0.0f);   // Z0 = Y
        a[k]  = 0.1f * y;                // mu1*X0 + G1_0 = mu1*Y
        g1[k] = 0.0f;
        bh[k] = 0.0f;
        bv[k] = 0.0f;
    }
    __syncthreads();

    float mu1 = 0.1f, mu2 = 0.1f;

    for (int it = 0; it < N_ITE; ++it) {
        const float mu2p   = mu2 * (1.0f / RHO_F);  // previous iteration's mu2
        const float inv_m2 = 1.0f / mu2;
        const float thr    = LAM_F * inv_m2;

        // ---- P1: shrink; bh_new = mu2*Uh + G21, bv_new = mu2*Uv + G22 ----
        #pragma unroll 4
        for (int k = 0; k < PXT; ++k) {
            int p    = tid + k * NT;
            int col  = p & (NSIDE - 1);
            int rowb = p & ~(NSIDE - 1);
            int sc_  = SW(col);
            float z  = C[rowb + sc_].x;
            float zl = C[rowb + SW((col + NSIDE - 1) & (NSIDE - 1))].x;
            int pu   = (p + NPIX - NSIDE) & (NPIX - 1);
            float zu = C[(pu & ~(NSIDE - 1)) + sc_].x;
            float dhz = z - zl;
            float dvz = z - zu;
            float g21 = (it == 0) ? 0.0f : fmaf(-mu2p, dhz, bh[k]);
            float g22 = (it == 0) ? 0.0f : fmaf(-mu2p, dvz, bv[k]);
            float ah = dhz - g21 * inv_m2;
            float av = dvz - g22 * inv_m2;
            float uh = copysignf(fmaxf(fabsf(ah) - thr, 0.0f), ah);
            float uv = copysignf(fmaxf(fabsf(av) - thr, 0.0f), av);
            bh[k] = fmaf(mu2, uh, g21);
            bv[k] = fmaf(mu2, uv, g22);
        }
        __syncthreads();          // all Z reads done before overwriting C

        // ---- P2: stage (bh, bv) in C for neighbor exchange ----
        #pragma unroll 4
        for (int k = 0; k < PXT; ++k) {
            int p = tid + k * NT;
            int col = p & (NSIDE - 1);
            int rowb = p & ~(NSIDE - 1);
            C[rowb + SW(col)] = make_float2(bh[k], bv[k]);
        }
        __syncthreads();

        // ---- P3: numerator = a + Dh^T bh + Dv^T bv ----
        float numv[PXT];
        #pragma unroll 4
        for (int k = 0; k < PXT; ++k) {
            int p    = tid + k * NT;
            int col  = p & (NSIDE - 1);
            int rowb = p & ~(NSIDE - 1);
            int sc_  = SW(col);
            float bhr = C[rowb + SW((col + 1) & (NSIDE - 1))].x;
            int pd    = (p + NSIDE) & (NPIX - 1);
            float bvd = C[(pd & ~(NSIDE - 1)) + sc_].y;
            numv[k] = a[k] + (bh[k] - bhr) + (bv[k] - bvd);
        }
        __syncthreads();          // all neighbor reads done before overwrite

        // ---- P4: C <- numerator (real) ----
        #pragma unroll 4
        for (int k = 0; k < PXT; ++k) {
            int p = tid + k * NT;
            int col = p & (NSIDE - 1);
            int rowb = p & ~(NSIDE - 1);
            C[rowb + SW(col)] = make_float2(numv[k], 0.0f);
        }
        __syncthreads();

        // ================= forward FFT over rows =================
        #define FWD_ROW_PASS(S, L2)                                          \
        {                                                                    \
            _Pragma("unroll 2")                                              \
            for (int q = 0; q < 4; ++q) {                                    \
                int m   = tid + q * NT;                                      \
                int rb  = (m >> 5) << 7;                                     \
                int b   = m & 31;                                            \
                int j   = b & ((L2) - 1);                                    \
                int i0  = ((b & ~((L2) - 1)) << 2) | j;                      \
                int e0 = rb + SW(i0);                                        \
                int e1 = rb + SW(i0 + (L2));                                 \
                int e2 = rb + SW(i0 + 2*(L2));                               \
                int e3 = rb + SW(i0 + 3*(L2));                               \
                float2 w1 = TW[j << (S)];                                    \
                float2 w2 = cmul(w1, w1);                                    \
                float2 x0 = C[e0], x1 = C[e1];                               \
                float2 x2 = C[e2], x3 = C[e3];                               \
                float2 t02p = cadd(x0, x2);                                  \
                float2 t13p = cadd(x1, x3);                                  \
                float2 t02m = cmul(csub(x0, x2), w1);                        \
                float2 uu   = cmul(csub(x1, x3), w1);                        \
                float2 t13m = make_float2(uu.y, -uu.x);   /* * (-i) */       \
                C[e0] = cadd(t02p, t13p);                                    \
                C[e1] = cmul(csub(t02p, t13p), w2);                          \
                C[e2] = cadd(t02m, t13m);                                    \
                C[e3] = cmul(csub(t02m, t13m), w2);                          \
            }                                                                \
            __syncthreads();                                                 \
        }
        FWD_ROW_PASS(0, 32)
        FWD_ROW_PASS(2, 8)
        // radix-8 pass: stages 4,5,6 on 8 consecutive cols (const twiddles)
        {
            #pragma unroll 2
            for (int q = 0; q < 2; ++q) {
                int m  = tid + q * NT;          // 0..2047 group index
                int rb = (m >> 4) << 7;         // row*128
                int cb = (m & 15) << 3;         // base col
                float2 zz[8];
                #pragma unroll
                for (int i = 0; i < 8; ++i) zz[i] = C[rb + SW(cb + i)];
                radix8_fwd(zz);
                #pragma unroll
                for (int i = 0; i < 8; ++i) C[rb + SW(cb + i)] = zz[i];
            }
            __syncthreads();
        }

        // ================= forward FFT over cols (2 radix-4 passes) =======
        #define FWD_COL_PASS(S, L2)                                          \
        {                                                                    \
            _Pragma("unroll 2")                                              \
            for (int q = 0; q < 4; ++q) {                                    \
                int m  = tid + q * NT;                                       \
                int c  = m & 127;                                            \
                int b  = m >> 7;                                             \
                int j  = b & ((L2) - 1);                                     \
                int i0 = ((b & ~((L2) - 1)) << 2) | j;                       \
                int p0 = (i0 << 7) + SW(c);                                  \
                const int ST = (L2) << 7;                                    \
                float2 w1 = TW[j << (S)];                                    \
                float2 w2 = cmul(w1, w1);                                    \
                float2 x0 = C[p0], x1 = C[p0 + ST];                          \
                float2 x2 = C[p0 + 2*ST], x3 = C[p0 + 3*ST];                 \
                float2 t02p = cadd(x0, x2);                                  \
                float2 t13p = cadd(x1, x3);                                  \
                float2 t02m = cmul(csub(x0, x2), w1);                        \
                float2 uu   = cmul(csub(x1, x3), w1);                        \
                float2 t13m = make_float2(uu.y, -uu.x);                      \
                C[p0]        = cadd(t02p, t13p);                             \
                C[p0 +   ST] = cmul(csub(t02p, t13p), w2);                   \
                C[p0 + 2*ST] = cadd(t02m, t13m);                             \
                C[p0 + 3*ST] = cmul(csub(t02m, t13m), w2);                   \
            }                                                                \
            __syncthreads();                                                 \
        }
        FWD_COL_PASS(0, 32)
        FWD_COL_PASS(2, 8)

        // ==== MEGA-PASS: cols fwd radix-8 (s=4,5,6) + solve x8 +
        //      cols inverse radix-8 (s=0,1,2), all in registers ====
        {
            const float sc = 1.0f / (float)NPIX;
            #pragma unroll 2
            for (int q = 0; q < 2; ++q) {
                int m   = tid + q * NT;
                int col = m & 127;
                int g   = m >> 7;               // 0..15 row-group
                int r0  = g << 3;               // base row
                int p0  = (r0 << 7) + SW(col);
                float2 zz[8];
                #pragma unroll
                for (int i = 0; i < 8; ++i) zz[i] = C[p0 + (i << 7)];
                radix8_fwd(zz);
                float d1c = D1[col];
                #pragma unroll
                for (int i = 0; i < 8; ++i) {
                    float f = sc / fmaf(mu2, D1[r0 + i] + d1c, mu1);
                    zz[i].x *= f; zz[i].y *= f;
                }
                radix8_inv(zz);
                #pragma unroll
                for (int i = 0; i < 8; ++i) C[p0 + (i << 7)] = zz[i];
            }
            __syncthreads();
        }

        // ================= inverse FFT over cols (2 radix-4 passes) =======
        #define INV_COL_PASS(SB, M)                                          \
        {                                                                    \
            _Pragma("unroll 2")                                              \
            for (int q = 0; q < 4; ++q) {                                    \
                int m  = tid + q * NT;                                       \
                int c  = m & 127;                                            \
                int b  = m >> 7;                                             \
                int j  = b & ((M) - 1);                                      \
                int i0 = ((b & ~((M) - 1)) << 2) | j;                        \
                int p0 = (i0 << 7) + SW(c);                                  \
                const int ST = (M) << 7;                                     \
                float2 wb = TW[j << (SB)];                                   \
                float2 wa = cmul(wb, wb);                                    \
                float2 x0 = C[p0], x1 = C[p0 + ST];                          \
                float2 x2 = C[p0 + 2*ST], x3 = C[p0 + 3*ST];                 \
                float2 pp1 = cmulc(x1, wa);                                  \
                float2 a0 = cadd(x0, pp1), a1 = csub(x0, pp1);               \
                float2 pp2 = cmulc(x3, wa);                                  \
                float2 a2 = cadd(x2, pp2), a3 = csub(x2, pp2);               \
                float2 q0 = cmulc(a2, wb);                                   \
                float2 y0 = cadd(a0, q0), y2 = csub(a0, q0);                 \
                float2 uu = cmulc(a3, wb);                                   \
                float2 q1 = make_float2(-uu.y, uu.x);     /* * (+i) */       \
                float2 y1 = cadd(a1, q1), y3 = csub(a1, q1);                 \
                C[p0]        = y0;                                           \
                C[p0 +   ST] = y1;                                           \
                C[p0 + 2*ST] = y2;                                           \
                C[p0 + 3*ST] = y3;                                           \
            }                                                                \
            __syncthreads();                                                 \
        }
        INV_COL_PASS(2, 8)
        INV_COL_PASS(0, 32)

        // ================= inverse FFT over rows =================
        // radix-8 pass: stages 0,1,2 on 8 consecutive cols (const twiddles)
        {
            #pragma unroll 2
            for (int q = 0; q < 2; ++q) {
                int m  = tid + q * NT;
                int rb = (m >> 4) << 7;
                int cb = (m & 15) << 3;
                float2 zz[8];
                #pragma unroll
                for (int i = 0; i < 8; ++i) zz[i] = C[rb + SW(cb + i)];
                radix8_inv(zz);
                #pragma unroll
                for (int i = 0; i < 8; ++i) C[rb + SW(cb + i)] = zz[i];
            }
            __syncthreads();
        }
        #define INV_ROW_PASS(SB, M)                                          \
        {                                                                    \
            _Pragma("unroll 2")                                              \
            for (int q = 0; q < 4; ++q) {                                    \
                int m   = tid + q * NT;                                      \
                int rb  = (m >> 5) << 7;                                     \
                int b   = m & 31;                                            \
                int j   = b & ((M) - 1);                                     \
                int i0  = ((b & ~((M) - 1)) << 2) | j;                       \
                int e0 = rb + SW(i0);                                        \
                int e1 = rb + SW(i0 + (M));                                  \
                int e2 = rb + SW(i0 + 2*(M));                                \
                int e3 = rb + SW(i0 + 3*(M));                                \
                float2 wb = TW[j << (SB)];                                   \
                float2 wa = cmul(wb, wb);                                    \
                float2 x0 = C[e0], x1 = C[e1];                               \
                float2 x2 = C[e2], x3 = C[e3];                               \
                float2 pp1 = cmulc(x1, wa);                                  \
                float2 a0 = cadd(x0, pp1), a1 = csub(x0, pp1);               \
                float2 pp2 = cmulc(x3, wa);                                  \
                float2 a2 = cadd(x2, pp2), a3 = csub(x2, pp2);               \
                float2 q0 = cmulc(a2, wb);                                   \
                float2 y0 = cadd(a0, q0), y2 = csub(a0, q0);                 \
                float2 uu = cmulc(a3, wb);                                   \
                float2 q1 = make_float2(-uu.y, uu.x);                        \
                float2 y1 = cadd(a1, q1), y3 = csub(a1, q1);                 \
                C[e0] = y0;                                                  \
                C[e1] = y1;                                                  \
                C[e2] = y2;                                                  \
                C[e3] = y3;                                                  \
            }                                                                \
            __syncthreads();                                                 \
        }
        INV_ROW_PASS(2, 8)
        INV_ROW_PASS(0, 32)

        // ---- Epilogue: X/G1/a update in registers; Z stays in C[].x ----
        const float mu1n = mu1 * RHO_F;
        #pragma unroll 4
        for (int k = 0; k < PXT; ++k) {
            int p = tid + k * NT;
            int col = p & (NSIDE - 1);
            int rowb = p & ~(NSIDE - 1);
            float z  = C[rowb + SW(col)].x;
            float y  = Y[p];
            float w  = Wt[p];
            float x  = fmaf(w, y, fmaf(mu1, z, -g1[k])) *
                       __builtin_amdgcn_rcpf(w + mu1);
            g1[k] = fmaf(mu1, x - z, g1[k]);
            a[k]  = fmaf(mu1n, x, g1[k]);
            if (it == N_ITE - 1) out[p] = z;
        }
        // no barrier needed: next P1 only reads C (covered by the FFT's last
        // barrier); P2's writes are behind P1's barrier.

        mu1 *= RHO_F;
        mu2 *= RHO_F;
    }
}

extern "C" void kernel_launch(void* const* d_in, const int* in_sizes, int n_in,
                              void* d_out, int out_size, void* d_ws, size_t ws_size,
                              hipStream_t stream) {
    (void)in_sizes; (void)n_in; (void)out_size; (void)d_ws; (void)ws_size;
    const float* Y   = (const float*)d_in[0];
    const float* inW = (const float*)d_in[1];
    float* out = (float*)d_out;

    const size_t smem_bytes = (size_t)NPIX * 8 + 64 * 8 + 128 * 4;  // 132096
    hipFuncSetAttribute((const void*)hwtv_kernel,
                        hipFuncAttributeMaxDynamicSharedMemorySize,
                        (int)smem_bytes);
    hipLaunchKernelGGL(hwtv_kernel, dim3(NIMG), dim3(NT), smem_bytes, stream,
                       Y, inW, out);
}